// Round 1
// baseline (376.232 us; speedup 1.0000x reference)
//
#include <hip/hip_runtime.h>
#include <stdint.h>

// BinaryConv2D: x (64,56,56,128) NHWC fp32, w (3,3,128,256) HWIO fp32.
// binarize(v) = v>=0 ? +1 : -1  (bit = 1 iff v < 0; -0.0f maps to +1 like the ref).
// dot over K valid elements = K - 2*popc(xbits ^ wbits).
// SAME padding: pad taps contribute 0 -> excluded from K and popc.

#define IH 56
#define IW 56
#define CIN 128
#define COUT 256
#define NBATCH 64

// ---- pack x: one wave per pixel-iteration, ballot over 64 lanes ----
__global__ void pack_x_kernel(const float* __restrict__ x,
                              uint64_t* __restrict__ xp, int npix) {
    int gtid = blockIdx.x * blockDim.x + threadIdx.x;
    int wave = gtid >> 6;
    int lane = gtid & 63;
    int nwaves = (gridDim.x * blockDim.x) >> 6;
    for (int p = wave; p < npix; p += nwaves) {
        float a = x[(size_t)p * CIN + lane];
        float b = x[(size_t)p * CIN + 64 + lane];
        uint64_t m0 = __ballot(a < 0.0f);   // bit i = channel i sign
        uint64_t m1 = __ballot(b < 0.0f);   // channels 64..127
        if (lane == 0) {
            xp[2 * (size_t)p]     = m0;
            xp[2 * (size_t)p + 1] = m1;
        }
    }
}

// ---- pack w: task = oc*9 + tap; lanes read strided (w is tiny, 1.2 MB) ----
__global__ void pack_w_kernel(const float* __restrict__ w,
                              uint64_t* __restrict__ wp) {
    int gtid = blockIdx.x * blockDim.x + threadIdx.x;
    int wave = gtid >> 6;
    int lane = gtid & 63;
    int nwaves = (gridDim.x * blockDim.x) >> 6;
    const int ntask = COUT * 9;
    for (int t = wave; t < ntask; t += nwaves) {
        int oc  = t / 9;
        int tap = t % 9;   // kh*3 + kw
        float a = w[((size_t)tap * CIN + lane) * COUT + oc];
        float b = w[((size_t)tap * CIN + 64 + lane) * COUT + oc];
        uint64_t m0 = __ballot(a < 0.0f);
        uint64_t m1 = __ballot(b < 0.0f);
        if (lane == 0) {
            wp[2 * (size_t)t]     = m0;
            wp[2 * (size_t)t + 1] = m1;
        }
    }
}

// ---- conv: block = (n,h) output row, thread = oc, loop over w ----
__global__ __launch_bounds__(256) void bconv_kernel(
        const uint64_t* __restrict__ xp,
        const uint64_t* __restrict__ wp,
        float* __restrict__ out) {
    __shared__ alignas(16) uint64_t xs[3][IW][2];   // 3 input rows, 2688 B

    int nh = blockIdx.x;          // n*56 + h
    int h  = nh % IH;
    int n  = nh / IH;
    int oc = threadIdx.x;

    // cooperative stage of rows h-1..h+1 into LDS (invalid rows never read)
    for (int i = threadIdx.x; i < 3 * IW; i += blockDim.x) {
        int kh = i / IW, c = i % IW;
        int r = h - 1 + kh;
        if ((unsigned)r < IH) {
            size_t p = ((size_t)n * IH + r) * IW + c;
            xs[kh][c][0] = xp[2 * p];
            xs[kh][c][1] = xp[2 * p + 1];
        }
    }

    // this thread's filter: 9 taps x 128 bits = 18 x u64 in VGPRs
    uint64_t wr[18];
#pragma unroll
    for (int t = 0; t < 9; ++t) {
        wr[2 * t]     = wp[((size_t)oc * 9 + t) * 2];
        wr[2 * t + 1] = wp[((size_t)oc * 9 + t) * 2 + 1];
    }
    __syncthreads();

    size_t obase = (size_t)nh * IW * COUT + oc;
    for (int w = 0; w < IW; ++w) {
        int popc = 0, valid = 0;
#pragma unroll
        for (int kh = 0; kh < 3; ++kh) {
            int r = h - 1 + kh;
            if ((unsigned)r >= IH) continue;       // block-uniform branch
#pragma unroll
            for (int kw = 0; kw < 3; ++kw) {
                int c = w - 1 + kw;
                if ((unsigned)c >= IW) continue;   // wave-uniform branch
                valid++;
                int t = kh * 3 + kw;
                popc += __popcll(xs[kh][c][0] ^ wr[2 * t])
                      + __popcll(xs[kh][c][1] ^ wr[2 * t + 1]);
            }
        }
        out[obase + (size_t)w * COUT] = (float)(valid * CIN - 2 * popc);
    }
}

extern "C" void kernel_launch(void* const* d_in, const int* in_sizes, int n_in,
                              void* d_out, int out_size, void* d_ws, size_t ws_size,
                              hipStream_t stream) {
    const float* x = (const float*)d_in[0];
    const float* w = (const float*)d_in[1];
    float* out = (float*)d_out;

    // workspace layout: [0, 36KB) packed w ; [64KB, 64KB+3.2MB) packed x
    uint64_t* wp = (uint64_t*)d_ws;
    uint64_t* xp = (uint64_t*)((char*)d_ws + (64 << 10));

    const int npix = NBATCH * IH * IW;   // 200704

    pack_x_kernel<<<2048, 256, 0, stream>>>(x, xp, npix);
    pack_w_kernel<<<144, 256, 0, stream>>>(w, wp);       // 576 waves, 2304 tasks
    bconv_kernel<<<NBATCH * IH, 256, 0, stream>>>(xp, wp, out);
}